// Round 6
// baseline (98.875 us; speedup 1.0000x reference)
//
#include <hip/hip_runtime.h>
#include <math.h>

#define LL 4096      // H*W
#define KK 256       // C
#define HH 64
#define WW 64
#define NHEAD 8
#define NPNT 16
#define HD 32        // C / NH

typedef unsigned short u16;
typedef __attribute__((ext_vector_type(8))) short sh8;
typedef __attribute__((ext_vector_type(4))) float f32x4;

__device__ __forceinline__ u16 f2bf(float x) {
    union { float f; unsigned u; } v; v.f = x;
    unsigned r = v.u + 0x7FFFu + ((v.u >> 16) & 1u);
    return (u16)(r >> 16);
}
__device__ __forceinline__ float bf2f(u16 h) {
    union { unsigned u; float f; } v; v.u = ((unsigned)h) << 16;
    return v.f;
}

// ---------------------------------------------------------------------------
// prep_k: fused input conversion.
// Blocks [0,512): feat (B,K,L) f32 -> featT (B*L, K) bf16 hi/lo (LDS transpose)
// Blocks [512,752): weight rows -> wcat hi/lo (+bias cat) and pw hi/lo.
//   wcat rows: [0,256) value | [256,512) offset | [512,640) att |
//              [640,656) size | [656,704) zero-pad.
// ---------------------------------------------------------------------------
__global__ __launch_bounds__(256) void prep_k(
    const float* __restrict__ feat,
    const float* __restrict__ vw,  const float* __restrict__ vb,
    const float* __restrict__ adw, const float* __restrict__ adb,
    const float* __restrict__ atw, const float* __restrict__ atb,
    const float* __restrict__ sw,  const float* __restrict__ sb,
    const float* __restrict__ pw,
    u16* __restrict__ th, u16* __restrict__ tl,
    u16* __restrict__ wh, u16* __restrict__ wl,
    float* __restrict__ bcat,
    u16* __restrict__ ph, u16* __restrict__ pl)
{
    __shared__ float T[64][68];
    const int bx = blockIdx.x;

    if (bx < 512) {
        const int b  = bx >> 8;
        const int k0 = (bx & 3) * 64;
        const int l0 = ((bx >> 2) & 63) * 64;
        const int c  = threadIdx.x & 15;
        const int rr = threadIdx.x >> 4;

        #pragma unroll
        for (int r = 0; r < 4; ++r) {
            const int kk = rr + r * 16;
            float4 v = *(const float4*)(feat + ((size_t)(b * KK + k0 + kk)) * LL + l0 + c * 4);
            T[c * 4 + 0][kk] = v.x; T[c * 4 + 1][kk] = v.y;
            T[c * 4 + 2][kk] = v.z; T[c * 4 + 3][kk] = v.w;
        }
        __syncthreads();
        #pragma unroll
        for (int r = 0; r < 4; ++r) {
            const int ll = rr + r * 16;
            float4 v = *(const float4*)&T[ll][c * 4];
            ushort4 hi, lo;
            float x;
            x = v.x; hi.x = f2bf(x); lo.x = f2bf(x - bf2f(hi.x));
            x = v.y; hi.y = f2bf(x); lo.y = f2bf(x - bf2f(hi.y));
            x = v.z; hi.z = f2bf(x); lo.z = f2bf(x - bf2f(hi.z));
            x = v.w; hi.w = f2bf(x); lo.w = f2bf(x - bf2f(hi.w));
            const size_t off = ((size_t)(b * LL + l0 + ll)) * KK + k0 + c * 4;
            *(ushort4*)(th + off) = hi;
            *(ushort4*)(tl + off) = lo;
        }
    } else {
        const int row = (bx - 512) * 4 + (threadIdx.x >> 6);  // 0..959
        const int c   = threadIdx.x & 63;

        const float* src = nullptr;
        float bv = 0.f;
        u16* dh; u16* dl;
        int drow;

        if (row < 704) {
            const int o = row;
            if (o < 256)      { src = vw  + (size_t)o * KK;        bv = vb[o]; }
            else if (o < 512) { src = adw + (size_t)(o-256) * KK;  bv = adb[o-256]; }
            else if (o < 640) { src = atw + (size_t)(o-512) * KK;  bv = atb[o-512]; }
            else if (o < 656) { src = sw  + (size_t)(o-640) * KK;  bv = sb[o-640]; }
            dh = wh; dl = wl; drow = o;
            if (c == 0) bcat[o] = bv;
        } else {
            const int o = row - 704;
            src = pw + (size_t)o * KK;
            dh = ph; dl = pl; drow = o;
        }

        float4 v = {0.f, 0.f, 0.f, 0.f};
        if (src) v = *(const float4*)(src + c * 4);
        ushort4 hi, lo;
        float x;
        x = v.x; hi.x = f2bf(x); lo.x = f2bf(x - bf2f(hi.x));
        x = v.y; hi.y = f2bf(x); lo.y = f2bf(x - bf2f(hi.y));
        x = v.z; hi.z = f2bf(x); lo.z = f2bf(x - bf2f(hi.z));
        x = v.w; hi.w = f2bf(x); lo.w = f2bf(x - bf2f(hi.w));
        const size_t off = (size_t)drow * KK + c * 4;
        *(ushort4*)(dh + off) = hi;
        *(ushort4*)(dl + off) = lo;
    }
}

// ---------------------------------------------------------------------------
// Projection MFMA GEMM: A=featT (M=8192 pixels), B=wcat (N=704), K=256.
// blockIdx.y < 4 (value cols, o<256): 1 MFMA (hi*hi), bf16 store -> mem2.
// else: split-precision 3-MFMA, f32 store -> rawp (pixel-major, 400 ch).
// One wave per block; 64x64 wave tile = 4x4 fragments of 16x16x32.
// ---------------------------------------------------------------------------
__global__ __launch_bounds__(64) void mgemm0_k(
    const u16* __restrict__ Ah, const u16* __restrict__ Al,
    const u16* __restrict__ Bh, const u16* __restrict__ Bl,
    const float* __restrict__ bias,
    u16* __restrict__ mem2, float* __restrict__ rawp)
{
    const int lam = threadIdx.x;
    const int m0 = blockIdx.x * 64;
    const int n0 = blockIdx.y * 64;
    const bool VAL = (blockIdx.y < 4);
    const int row = lam & 15;
    const int kq  = (lam >> 4) * 8;

    f32x4 acc[4][4];
    #pragma unroll
    for (int i = 0; i < 4; ++i)
        #pragma unroll
        for (int j = 0; j < 4; ++j)
            acc[i][j] = (f32x4){0.f, 0.f, 0.f, 0.f};

    #pragma unroll
    for (int s = 0; s < 8; ++s) {
        const int k0 = s * 32;
        sh8 ah[4], bh[4];
        #pragma unroll
        for (int mf = 0; mf < 4; ++mf)
            ah[mf] = *(const sh8*)(Ah + ((size_t)(m0 + mf * 16 + row)) * KK + k0 + kq);
        #pragma unroll
        for (int nf = 0; nf < 4; ++nf)
            bh[nf] = *(const sh8*)(Bh + ((size_t)(n0 + nf * 16 + row)) * KK + k0 + kq);

        if (VAL) {
            #pragma unroll
            for (int mf = 0; mf < 4; ++mf)
                #pragma unroll
                for (int nf = 0; nf < 4; ++nf)
                    acc[mf][nf] = __builtin_amdgcn_mfma_f32_16x16x32_bf16(ah[mf], bh[nf], acc[mf][nf], 0, 0, 0);
        } else {
            sh8 al[4], bl[4];
            #pragma unroll
            for (int mf = 0; mf < 4; ++mf)
                al[mf] = *(const sh8*)(Al + ((size_t)(m0 + mf * 16 + row)) * KK + k0 + kq);
            #pragma unroll
            for (int nf = 0; nf < 4; ++nf)
                bl[nf] = *(const sh8*)(Bl + ((size_t)(n0 + nf * 16 + row)) * KK + k0 + kq);
            #pragma unroll
            for (int mf = 0; mf < 4; ++mf)
                #pragma unroll
                for (int nf = 0; nf < 4; ++nf) {
                    acc[mf][nf] = __builtin_amdgcn_mfma_f32_16x16x32_bf16(ah[mf], bh[nf], acc[mf][nf], 0, 0, 0);
                    acc[mf][nf] = __builtin_amdgcn_mfma_f32_16x16x32_bf16(ah[mf], bl[nf], acc[mf][nf], 0, 0, 0);
                    acc[mf][nf] = __builtin_amdgcn_mfma_f32_16x16x32_bf16(al[mf], bh[nf], acc[mf][nf], 0, 0, 0);
                }
        }
    }

    float bj[4];
    #pragma unroll
    for (int nf = 0; nf < 4; ++nf) bj[nf] = bias[n0 + nf * 16 + row];

    #pragma unroll
    for (int mf = 0; mf < 4; ++mf)
        #pragma unroll
        for (int r = 0; r < 4; ++r) {
            const int m = m0 + mf * 16 + 4 * (lam >> 4) + r;   // global pixel
            const int b  = m >> 12;
            const int ll = m & (LL - 1);
            #pragma unroll
            for (int nf = 0; nf < 4; ++nf) {
                const int o = n0 + nf * 16 + row;
                const float v = acc[mf][nf][r] + bj[nf];
                if (VAL) {
                    mem2[(((size_t)(b * NHEAD + (o >> 5)) * LL + ll) * HD) + (o & 31)] = f2bf(v);
                } else if (o < 640) {
                    rawp[((size_t)(b * LL + ll)) * 400 + (o - 240)] = v;   // offset/att: ch 16..399
                } else if (o < 656) {
                    rawp[((size_t)(b * LL + ll)) * 400 + (o - 640)] = v;   // size: ch 0..15
                }
            }
        }
}

// ---------------------------------------------------------------------------
// Fused sampling + out-projection + BN.
// Block = 32 pixels (one b), 256 threads. Loop h=0..7:
//   phase 1: 512 (px,p) tasks -> shfl softmax, sigmoids, bilinear weights
//            -> LDS records.
//   phase 2: 8 lanes/px, 4ch each: bf16 gathers from mem2, accumulate,
//            store bf16 into LDS pre[32][264] (pad => conflict-free MFMA reads).
// Then: 4 waves x (64 out-ch x 32 px) split-MFMA with pw hi/lo, BN, store.
// ---------------------------------------------------------------------------
__global__ __launch_bounds__(256) void sampout_k(
    const u16* __restrict__ mem2,
    const float* __restrict__ rawp,
    const u16* __restrict__ pwh, const u16* __restrict__ pwl,
    const float* __restrict__ gamma, const float* __restrict__ beta,
    float* __restrict__ out)
{
    __shared__ int   soff[32][17][4];
    __shared__ float swt[32][17][4];
    __shared__ u16   pre[32][264];     // [px][ch], 264-pad

    const int tid = threadIdx.x;
    const int bpx = blockIdx.x;        // 0..255
    const int b   = bpx >> 7;
    const int l0  = (bpx & 127) * 32;

    for (int h = 0; h < NHEAD; ++h) {
        // ---- phase 1: 32 px x 16 points = 512 tasks ----
        #pragma unroll
        for (int q = 0; q < 2; ++q) {
            const int t   = q * 256 + tid;
            const int pxi = t >> 4;
            const int p   = t & 15;
            const int l   = l0 + pxi;
            const float* rb = rawp + ((size_t)(b * LL + l)) * 400;

            float logit = rb[272 + h * NPNT + p];
            float m = logit;
            m = fmaxf(m, __shfl_xor(m, 1));
            m = fmaxf(m, __shfl_xor(m, 2));
            m = fmaxf(m, __shfl_xor(m, 4));
            m = fmaxf(m, __shfl_xor(m, 8));
            float e = __expf(logit - m);
            float s = e;
            s += __shfl_xor(s, 1);
            s += __shfl_xor(s, 2);
            s += __shfl_xor(s, 4);
            s += __shfl_xor(s, 8);
            const float wp = e / s;

            float s0 = rb[h * 2 + 0];
            float s1 = rb[h * 2 + 1];
            s0 = fminf(fmaxf(1.f / (1.f + __expf(-s0)), 0.25f), 0.75f);
            s1 = fminf(fmaxf(1.f / (1.f + __expf(-s1)), 0.25f), 0.75f);

            float o0 = rb[16 + (h * NPNT + p) * 2 + 0];
            float o1 = rb[16 + (h * NPNT + p) * 2 + 1];
            o0 = 1.f / (1.f + __expf(-o0));
            o1 = 1.f / (1.f + __expf(-o1));

            const int xl = l & (WW - 1);
            const int yl = l >> 6;
            const float cx = ((float)xl + 0.5f) / ((float)WW + 1e-6f);
            const float cy = ((float)yl + 0.5f) / ((float)HH + 1e-6f);

            float gx = fminf(fmaxf(cx - 0.5f * s0 + o0 * s0, 0.f), 1.f);
            float gy = fminf(fmaxf(cy - 0.5f * s1 + o1 * s1, 0.f), 1.f);
            const float ix = gx * (float)(WW - 1);
            const float iy = gy * (float)(HH - 1);
            const float x0f = floorf(ix);
            const float y0f = floorf(iy);
            const float wx = ix - x0f;
            const float wy = iy - y0f;
            int x0 = min(max((int)x0f, 0), WW - 1);
            int x1 = min(x0 + 1, WW - 1);
            int y0 = min(max((int)y0f, 0), HH - 1);
            int y1 = min(y0 + 1, HH - 1);

            soff[pxi][p][0] = (y0 * WW + x0) * HD;
            soff[pxi][p][1] = (y0 * WW + x1) * HD;
            soff[pxi][p][2] = (y1 * WW + x0) * HD;
            soff[pxi][p][3] = (y1 * WW + x1) * HD;
            swt[pxi][p][0] = wp * (1.f - wx) * (1.f - wy);
            swt[pxi][p][1] = wp * wx * (1.f - wy);
            swt[pxi][p][2] = wp * (1.f - wx) * wy;
            swt[pxi][p][3] = wp * wx * wy;
        }
        __syncthreads();

        // ---- phase 2: gather-accumulate, 8 lanes per pixel ----
        {
            const int gi = tid >> 3;          // px 0..31
            const int dq = (tid & 7) * 4;     // channel quad within head
            const u16* mb = mem2 + (size_t)(b * NHEAD + h) * LL * HD + dq;

            float4 acc = {0.f, 0.f, 0.f, 0.f};
            #pragma unroll
            for (int p = 0; p < NPNT; ++p) {
                const int4   off = *(const int4*)&soff[gi][p][0];
                const float4 w   = *(const float4*)&swt[gi][p][0];
                const ushort4 q00 = *(const ushort4*)(mb + off.x);
                const ushort4 q01 = *(const ushort4*)(mb + off.y);
                const ushort4 q10 = *(const ushort4*)(mb + off.z);
                const ushort4 q11 = *(const ushort4*)(mb + off.w);
                acc.x += w.x * bf2f(q00.x) + w.y * bf2f(q01.x) + w.z * bf2f(q10.x) + w.w * bf2f(q11.x);
                acc.y += w.x * bf2f(q00.y) + w.y * bf2f(q01.y) + w.z * bf2f(q10.y) + w.w * bf2f(q11.y);
                acc.z += w.x * bf2f(q00.z) + w.y * bf2f(q01.z) + w.z * bf2f(q10.z) + w.w * bf2f(q11.z);
                acc.w += w.x * bf2f(q00.w) + w.y * bf2f(q01.w) + w.z * bf2f(q10.w) + w.w * bf2f(q11.w);
            }
            ushort4 hi;
            hi.x = f2bf(acc.x); hi.y = f2bf(acc.y); hi.z = f2bf(acc.z); hi.w = f2bf(acc.w);
            *(ushort4*)&pre[gi][h * HD + dq] = hi;
        }
        __syncthreads();   // records reusable; pre visible at the end
    }

    // ---- out projection + BN: 4 waves x (64 ch x 32 px) ----
    const int lam = tid & 63;
    const int wid = tid >> 6;
    const int m0  = wid * 64;
    const int row = lam & 15;
    const int kq  = (lam >> 4) * 8;

    f32x4 acc[4][2];
    #pragma unroll
    for (int i = 0; i < 4; ++i)
        #pragma unroll
        for (int j = 0; j < 2; ++j)
            acc[i][j] = (f32x4){0.f, 0.f, 0.f, 0.f};

    #pragma unroll
    for (int s = 0; s < 8; ++s) {
        const int k0 = s * 32;
        sh8 ah[4], al[4], bh[2];
        #pragma unroll
        for (int mf = 0; mf < 4; ++mf) {
            const size_t off = ((size_t)(m0 + mf * 16 + row)) * KK + k0 + kq;
            ah[mf] = *(const sh8*)(pwh + off);
            al[mf] = *(const sh8*)(pwl + off);
        }
        #pragma unroll
        for (int nf = 0; nf < 2; ++nf)
            bh[nf] = *(const sh8*)&pre[nf * 16 + row][k0 + kq];
        #pragma unroll
        for (int mf = 0; mf < 4; ++mf)
            #pragma unroll
            for (int nf = 0; nf < 2; ++nf) {
                acc[mf][nf] = __builtin_amdgcn_mfma_f32_16x16x32_bf16(ah[mf], bh[nf], acc[mf][nf], 0, 0, 0);
                acc[mf][nf] = __builtin_amdgcn_mfma_f32_16x16x32_bf16(al[mf], bh[nf], acc[mf][nf], 0, 0, 0);
            }
    }

    #pragma unroll
    for (int mf = 0; mf < 4; ++mf)
        #pragma unroll
        for (int r = 0; r < 4; ++r) {
            const int o = m0 + mf * 16 + 4 * (lam >> 4) + r;   // channel
            const float sc = gamma[o] / sqrtf(1.f + 1e-5f);
            const float be = beta[o];
            #pragma unroll
            for (int nf = 0; nf < 2; ++nf) {
                const int ll = l0 + nf * 16 + row;             // pixel in image
                out[((size_t)(b * KK + o)) * LL + ll] = acc[mf][nf][r] * sc + be;
            }
        }
}

extern "C" void kernel_launch(void* const* d_in, const int* in_sizes, int n_in,
                              void* d_out, int out_size, void* d_ws, size_t ws_size,
                              hipStream_t stream) {
    const float* feat  = (const float*)d_in[0];
    const float* vw    = (const float*)d_in[1];
    const float* vb    = (const float*)d_in[2];
    const float* sw    = (const float*)d_in[3];
    const float* sb    = (const float*)d_in[4];
    const float* adw   = (const float*)d_in[5];
    const float* adb   = (const float*)d_in[6];
    const float* atw   = (const float*)d_in[7];
    const float* atb   = (const float*)d_in[8];
    const float* pw    = (const float*)d_in[9];
    const float* gamma = (const float*)d_in[10];
    const float* beta  = (const float*)d_in[11];
    float* out = (float*)d_out;
    char* ws = (char*)d_ws;

    // workspace layout (bytes)
    u16* featTh = (u16*)(ws + 0);          // 4 MB
    u16* featTl = (u16*)(ws + 4194304);    // 4 MB
    u16* mem2   = (u16*)(ws + 8388608);    // 4 MB (bf16)
    float* rawp = (float*)(ws + 12582912); // 13.1 MB
    u16* wch    = (u16*)(ws + 25690112);   // 352 KB
    u16* wcl    = (u16*)(ws + 26050560);   // 352 KB
    float* bcat = (float*)(ws + 26411008); // 2.8 KB
    u16* pwh    = (u16*)(ws + 26413824);   // 128 KB
    u16* pwl    = (u16*)(ws + 26544896);   // 128 KB

    // input conversions (feat transpose + all weights), one launch
    prep_k<<<dim3(752), dim3(256), 0, stream>>>(feat, vw, vb, adw, adb, atw, atb,
                                                sw, sb, pw, featTh, featTl,
                                                wch, wcl, bcat, pwh, pwl);
    // all projections; value cols 1-MFMA -> bf16 mem2, rest 3-MFMA -> rawp
    mgemm0_k<<<dim3(128, 11), dim3(64), 0, stream>>>(featTh, featTl, wch, wcl, bcat,
                                                     mem2, rawp);
    // fused sampling + out-projection + BN
    sampout_k<<<dim3(256), dim3(256), 0, stream>>>(mem2, rawp, pwh, pwl,
                                                   gamma, beta, out);
}

// Round 7
// 73.684 us; speedup vs baseline: 1.3419x; 1.3419x over previous
//
#include <hip/hip_runtime.h>
#include <math.h>

#define LL 4096      // H*W
#define KK 256       // C
#define HH 64
#define WW 64
#define NHEAD 8
#define NPNT 16
#define HD 32        // C / NH

typedef unsigned short u16;
typedef __attribute__((ext_vector_type(8))) short sh8;
typedef __attribute__((ext_vector_type(4))) float f32x4;

__device__ __forceinline__ u16 f2bf(float x) {
    union { float f; unsigned u; } v; v.f = x;
    unsigned r = v.u + 0x7FFFu + ((v.u >> 16) & 1u);
    return (u16)(r >> 16);
}
__device__ __forceinline__ float bf2f(u16 h) {
    union { unsigned u; float f; } v; v.u = ((unsigned)h) << 16;
    return v.f;
}

// ---------------------------------------------------------------------------
// prep_k: fused input conversion.
// Blocks [0,512): feat (B,K,L) f32 -> featT (B*L, K) bf16 hi/lo (LDS transpose)
// Blocks [512,752): weight rows -> wcat hi/lo (+bias cat) and pw hi/lo.
//   wcat rows: [0,256) value | [256,512) offset | [512,640) att |
//              [640,656) size | [656,704) zero-pad.
// ---------------------------------------------------------------------------
__global__ __launch_bounds__(256) void prep_k(
    const float* __restrict__ feat,
    const float* __restrict__ vw,  const float* __restrict__ vb,
    const float* __restrict__ adw, const float* __restrict__ adb,
    const float* __restrict__ atw, const float* __restrict__ atb,
    const float* __restrict__ sw,  const float* __restrict__ sb,
    const float* __restrict__ pw,
    u16* __restrict__ th, u16* __restrict__ tl,
    u16* __restrict__ wh, u16* __restrict__ wl,
    float* __restrict__ bcat,
    u16* __restrict__ ph, u16* __restrict__ pl)
{
    __shared__ float T[64][68];
    const int bx = blockIdx.x;

    if (bx < 512) {
        const int b  = bx >> 8;
        const int k0 = (bx & 3) * 64;
        const int l0 = ((bx >> 2) & 63) * 64;
        const int c  = threadIdx.x & 15;
        const int rr = threadIdx.x >> 4;

        #pragma unroll
        for (int r = 0; r < 4; ++r) {
            const int kk = rr + r * 16;
            float4 v = *(const float4*)(feat + ((size_t)(b * KK + k0 + kk)) * LL + l0 + c * 4);
            T[c * 4 + 0][kk] = v.x; T[c * 4 + 1][kk] = v.y;
            T[c * 4 + 2][kk] = v.z; T[c * 4 + 3][kk] = v.w;
        }
        __syncthreads();
        #pragma unroll
        for (int r = 0; r < 4; ++r) {
            const int ll = rr + r * 16;
            float4 v = *(const float4*)&T[ll][c * 4];
            ushort4 hi, lo;
            float x;
            x = v.x; hi.x = f2bf(x); lo.x = f2bf(x - bf2f(hi.x));
            x = v.y; hi.y = f2bf(x); lo.y = f2bf(x - bf2f(hi.y));
            x = v.z; hi.z = f2bf(x); lo.z = f2bf(x - bf2f(hi.z));
            x = v.w; hi.w = f2bf(x); lo.w = f2bf(x - bf2f(hi.w));
            const size_t off = ((size_t)(b * LL + l0 + ll)) * KK + k0 + c * 4;
            *(ushort4*)(th + off) = hi;
            *(ushort4*)(tl + off) = lo;
        }
    } else {
        const int row = (bx - 512) * 4 + (threadIdx.x >> 6);  // 0..959
        const int c   = threadIdx.x & 63;

        const float* src = nullptr;
        float bv = 0.f;
        u16* dh; u16* dl;
        int drow;

        if (row < 704) {
            const int o = row;
            if (o < 256)      { src = vw  + (size_t)o * KK;        bv = vb[o]; }
            else if (o < 512) { src = adw + (size_t)(o-256) * KK;  bv = adb[o-256]; }
            else if (o < 640) { src = atw + (size_t)(o-512) * KK;  bv = atb[o-512]; }
            else if (o < 656) { src = sw  + (size_t)(o-640) * KK;  bv = sb[o-640]; }
            dh = wh; dl = wl; drow = o;
            if (c == 0) bcat[o] = bv;
        } else {
            const int o = row - 704;
            src = pw + (size_t)o * KK;
            dh = ph; dl = pl; drow = o;
        }

        float4 v = {0.f, 0.f, 0.f, 0.f};
        if (src) v = *(const float4*)(src + c * 4);
        ushort4 hi, lo;
        float x;
        x = v.x; hi.x = f2bf(x); lo.x = f2bf(x - bf2f(hi.x));
        x = v.y; hi.y = f2bf(x); lo.y = f2bf(x - bf2f(hi.y));
        x = v.z; hi.z = f2bf(x); lo.z = f2bf(x - bf2f(hi.z));
        x = v.w; hi.w = f2bf(x); lo.w = f2bf(x - bf2f(hi.w));
        const size_t off = (size_t)drow * KK + c * 4;
        *(ushort4*)(dh + off) = hi;
        *(ushort4*)(dl + off) = lo;
    }
}

// ---------------------------------------------------------------------------
// Projection MFMA GEMM: A=featT (M=8192 pixels), B=wcat (N=704), K=256.
// Wave tile 32x64 (2x4 fragments) -> grid (256, 11) = 2816 waves (~11/CU)
// for latency hiding (was 64x64, 5.5 waves/CU, latency-exposed).
// blockIdx.y < 4 (value cols, o<256): 1 MFMA (hi*hi), bf16 store -> mem2.
// else: split-precision 3-MFMA, f32 store -> rawp (pixel-major, 400 ch).
// ---------------------------------------------------------------------------
__global__ __launch_bounds__(64) void mgemm0_k(
    const u16* __restrict__ Ah, const u16* __restrict__ Al,
    const u16* __restrict__ Bh, const u16* __restrict__ Bl,
    const float* __restrict__ bias,
    u16* __restrict__ mem2, float* __restrict__ rawp)
{
    const int lam = threadIdx.x;
    const int m0 = blockIdx.x * 32;
    const int n0 = blockIdx.y * 64;
    const bool VAL = (blockIdx.y < 4);
    const int row = lam & 15;
    const int kq  = (lam >> 4) * 8;

    f32x4 acc[2][4];
    #pragma unroll
    for (int i = 0; i < 2; ++i)
        #pragma unroll
        for (int j = 0; j < 4; ++j)
            acc[i][j] = (f32x4){0.f, 0.f, 0.f, 0.f};

    #pragma unroll
    for (int s = 0; s < 8; ++s) {
        const int k0 = s * 32;
        sh8 ah[2], bh[4];
        #pragma unroll
        for (int mf = 0; mf < 2; ++mf)
            ah[mf] = *(const sh8*)(Ah + ((size_t)(m0 + mf * 16 + row)) * KK + k0 + kq);
        #pragma unroll
        for (int nf = 0; nf < 4; ++nf)
            bh[nf] = *(const sh8*)(Bh + ((size_t)(n0 + nf * 16 + row)) * KK + k0 + kq);

        if (VAL) {
            #pragma unroll
            for (int mf = 0; mf < 2; ++mf)
                #pragma unroll
                for (int nf = 0; nf < 4; ++nf)
                    acc[mf][nf] = __builtin_amdgcn_mfma_f32_16x16x32_bf16(ah[mf], bh[nf], acc[mf][nf], 0, 0, 0);
        } else {
            sh8 al[2], bl[4];
            #pragma unroll
            for (int mf = 0; mf < 2; ++mf)
                al[mf] = *(const sh8*)(Al + ((size_t)(m0 + mf * 16 + row)) * KK + k0 + kq);
            #pragma unroll
            for (int nf = 0; nf < 4; ++nf)
                bl[nf] = *(const sh8*)(Bl + ((size_t)(n0 + nf * 16 + row)) * KK + k0 + kq);
            #pragma unroll
            for (int mf = 0; mf < 2; ++mf)
                #pragma unroll
                for (int nf = 0; nf < 4; ++nf) {
                    acc[mf][nf] = __builtin_amdgcn_mfma_f32_16x16x32_bf16(ah[mf], bh[nf], acc[mf][nf], 0, 0, 0);
                    acc[mf][nf] = __builtin_amdgcn_mfma_f32_16x16x32_bf16(ah[mf], bl[nf], acc[mf][nf], 0, 0, 0);
                    acc[mf][nf] = __builtin_amdgcn_mfma_f32_16x16x32_bf16(al[mf], bh[nf], acc[mf][nf], 0, 0, 0);
                }
        }
    }

    float bj[4];
    #pragma unroll
    for (int nf = 0; nf < 4; ++nf) bj[nf] = bias[n0 + nf * 16 + row];

    #pragma unroll
    for (int mf = 0; mf < 2; ++mf)
        #pragma unroll
        for (int r = 0; r < 4; ++r) {
            const int m = m0 + mf * 16 + 4 * (lam >> 4) + r;   // global pixel
            const int b  = m >> 12;
            const int ll = m & (LL - 1);
            #pragma unroll
            for (int nf = 0; nf < 4; ++nf) {
                const int o = n0 + nf * 16 + row;
                const float v = acc[mf][nf][r] + bj[nf];
                if (VAL) {
                    mem2[(((size_t)(b * NHEAD + (o >> 5)) * LL + ll) * HD) + (o & 31)] = f2bf(v);
                } else if (o < 640) {
                    rawp[((size_t)(b * LL + ll)) * 400 + (o - 240)] = v;   // offset/att: ch 16..399
                } else if (o < 656) {
                    rawp[((size_t)(b * LL + ll)) * 400 + (o - 640)] = v;   // size: ch 0..15
                }
            }
        }
}

// ---------------------------------------------------------------------------
// Out projection + BN: A = pw hi/lo (M=256 ch), B = preT bf16 single
// (N=8192 pixels), 2 MFMAs per fragment pair.
// ---------------------------------------------------------------------------
__global__ __launch_bounds__(64) void mgemm1_k(
    const u16* __restrict__ Ah, const u16* __restrict__ Al,
    const u16* __restrict__ Bh,
    const float* __restrict__ gamma, const float* __restrict__ beta,
    float* __restrict__ out)
{
    const int lam = threadIdx.x;
    const int m0 = blockIdx.x * 64;
    const int n0 = blockIdx.y * 64;
    const int row = lam & 15;
    const int kq  = (lam >> 4) * 8;

    f32x4 acc[4][4];
    #pragma unroll
    for (int i = 0; i < 4; ++i)
        #pragma unroll
        for (int j = 0; j < 4; ++j)
            acc[i][j] = (f32x4){0.f, 0.f, 0.f, 0.f};

    #pragma unroll
    for (int s = 0; s < 8; ++s) {
        const int k0 = s * 32;
        sh8 ah[4], al[4], bh[4];
        #pragma unroll
        for (int mf = 0; mf < 4; ++mf) {
            const size_t off = ((size_t)(m0 + mf * 16 + row)) * KK + k0 + kq;
            ah[mf] = *(const sh8*)(Ah + off);
            al[mf] = *(const sh8*)(Al + off);
        }
        #pragma unroll
        for (int nf = 0; nf < 4; ++nf)
            bh[nf] = *(const sh8*)(Bh + ((size_t)(n0 + nf * 16 + row)) * KK + k0 + kq);
        #pragma unroll
        for (int mf = 0; mf < 4; ++mf)
            #pragma unroll
            for (int nf = 0; nf < 4; ++nf) {
                acc[mf][nf] = __builtin_amdgcn_mfma_f32_16x16x32_bf16(ah[mf], bh[nf], acc[mf][nf], 0, 0, 0);
                acc[mf][nf] = __builtin_amdgcn_mfma_f32_16x16x32_bf16(al[mf], bh[nf], acc[mf][nf], 0, 0, 0);
            }
    }

    #pragma unroll
    for (int mf = 0; mf < 4; ++mf)
        #pragma unroll
        for (int r = 0; r < 4; ++r) {
            const int o = m0 + mf * 16 + 4 * (lam >> 4) + r;   // channel
            const float sc = gamma[o] / sqrtf(1.f + 1e-5f);
            const float be = beta[o];
            #pragma unroll
            for (int nf = 0; nf < 4; ++nf) {
                const int lg = n0 + nf * 16 + row;             // global pixel
                const int b  = lg >> 12;
                const int ll = lg & (LL - 1);
                out[((size_t)(b * KK + o)) * LL + ll] = acc[mf][nf][r] * sc + be;
            }
        }
}

// ---------------------------------------------------------------------------
// Sampling: phase 1 (per (group,point) task, shfl softmax) -> LDS records;
// phase 2: 8 lanes/group, ushort4 bf16 gathers from mem2; emits preT bf16.
// rawp pixel-major: c 0..15 size, 16..271 offset, 272..399 att.
// ---------------------------------------------------------------------------
__global__ __launch_bounds__(256) void sample4_k(
    const u16* __restrict__ mem2,
    const float* __restrict__ rawp,
    u16* __restrict__ preH)
{
    __shared__ int   soff[32][17][4];
    __shared__ float swt[32][17][4];

    const int tid = threadIdx.x;

    #pragma unroll
    for (int q = 0; q < 2; ++q) {
        const int t  = q * 256 + tid;
        const int gi = t >> 4;
        const int p  = t & 15;
        const int g  = blockIdx.x * 32 + gi;
        const int l  = g & (LL - 1);
        const int h  = (g >> 12) & (NHEAD - 1);
        const int b  = g >> 15;
        const float* rb = rawp + ((size_t)(b * LL + l)) * 400;

        float logit = rb[272 + h * NPNT + p];
        float m = logit;
        m = fmaxf(m, __shfl_xor(m, 1));
        m = fmaxf(m, __shfl_xor(m, 2));
        m = fmaxf(m, __shfl_xor(m, 4));
        m = fmaxf(m, __shfl_xor(m, 8));
        float e = __expf(logit - m);
        float s = e;
        s += __shfl_xor(s, 1);
        s += __shfl_xor(s, 2);
        s += __shfl_xor(s, 4);
        s += __shfl_xor(s, 8);
        const float wp = e / s;

        float s0 = rb[h * 2 + 0];
        float s1 = rb[h * 2 + 1];
        s0 = fminf(fmaxf(1.f / (1.f + __expf(-s0)), 0.25f), 0.75f);
        s1 = fminf(fmaxf(1.f / (1.f + __expf(-s1)), 0.25f), 0.75f);

        float o0 = rb[16 + (h * NPNT + p) * 2 + 0];
        float o1 = rb[16 + (h * NPNT + p) * 2 + 1];
        o0 = 1.f / (1.f + __expf(-o0));
        o1 = 1.f / (1.f + __expf(-o1));

        const int xl = l & (WW - 1);
        const int yl = l >> 6;
        const float cx = ((float)xl + 0.5f) / ((float)WW + 1e-6f);
        const float cy = ((float)yl + 0.5f) / ((float)HH + 1e-6f);

        float gx = fminf(fmaxf(cx - 0.5f * s0 + o0 * s0, 0.f), 1.f);
        float gy = fminf(fmaxf(cy - 0.5f * s1 + o1 * s1, 0.f), 1.f);
        const float ix = gx * (float)(WW - 1);
        const float iy = gy * (float)(HH - 1);
        const float x0f = floorf(ix);
        const float y0f = floorf(iy);
        const float wx = ix - x0f;
        const float wy = iy - y0f;
        int x0 = min(max((int)x0f, 0), WW - 1);
        int x1 = min(x0 + 1, WW - 1);
        int y0 = min(max((int)y0f, 0), HH - 1);
        int y1 = min(y0 + 1, HH - 1);

        soff[gi][p][0] = (y0 * WW + x0) * HD;
        soff[gi][p][1] = (y0 * WW + x1) * HD;
        soff[gi][p][2] = (y1 * WW + x0) * HD;
        soff[gi][p][3] = (y1 * WW + x1) * HD;
        swt[gi][p][0] = wp * (1.f - wx) * (1.f - wy);
        swt[gi][p][1] = wp * wx * (1.f - wy);
        swt[gi][p][2] = wp * (1.f - wx) * wy;
        swt[gi][p][3] = wp * wx * wy;
    }
    __syncthreads();

    const int gi = tid >> 3;
    const int dq = (tid & 7) * 4;
    const int g  = blockIdx.x * 32 + gi;
    const int l  = g & (LL - 1);
    const int h  = (g >> 12) & (NHEAD - 1);
    const int b  = g >> 15;
    const u16* mb = mem2 + (size_t)(b * NHEAD + h) * LL * HD + dq;

    float4 acc = {0.f, 0.f, 0.f, 0.f};
    #pragma unroll
    for (int p = 0; p < NPNT; ++p) {
        const int4   off = *(const int4*)&soff[gi][p][0];
        const float4 w   = *(const float4*)&swt[gi][p][0];
        const ushort4 q00 = *(const ushort4*)(mb + off.x);
        const ushort4 q01 = *(const ushort4*)(mb + off.y);
        const ushort4 q10 = *(const ushort4*)(mb + off.z);
        const ushort4 q11 = *(const ushort4*)(mb + off.w);
        acc.x += w.x * bf2f(q00.x) + w.y * bf2f(q01.x) + w.z * bf2f(q10.x) + w.w * bf2f(q11.x);
        acc.y += w.x * bf2f(q00.y) + w.y * bf2f(q01.y) + w.z * bf2f(q10.y) + w.w * bf2f(q11.y);
        acc.z += w.x * bf2f(q00.z) + w.y * bf2f(q01.z) + w.z * bf2f(q10.z) + w.w * bf2f(q11.z);
        acc.w += w.x * bf2f(q00.w) + w.y * bf2f(q01.w) + w.z * bf2f(q10.w) + w.w * bf2f(q11.w);
    }

    ushort4 hi;
    hi.x = f2bf(acc.x); hi.y = f2bf(acc.y); hi.z = f2bf(acc.z); hi.w = f2bf(acc.w);
    *(ushort4*)(preH + ((size_t)(b * LL + l)) * KK + h * HD + dq) = hi;
}

extern "C" void kernel_launch(void* const* d_in, const int* in_sizes, int n_in,
                              void* d_out, int out_size, void* d_ws, size_t ws_size,
                              hipStream_t stream) {
    const float* feat  = (const float*)d_in[0];
    const float* vw    = (const float*)d_in[1];
    const float* vb    = (const float*)d_in[2];
    const float* sw    = (const float*)d_in[3];
    const float* sb    = (const float*)d_in[4];
    const float* adw   = (const float*)d_in[5];
    const float* adb   = (const float*)d_in[6];
    const float* atw   = (const float*)d_in[7];
    const float* atb   = (const float*)d_in[8];
    const float* pw    = (const float*)d_in[9];
    const float* gamma = (const float*)d_in[10];
    const float* beta  = (const float*)d_in[11];
    float* out = (float*)d_out;
    char* ws = (char*)d_ws;

    // workspace layout (bytes); featT region is reused for preT after proj GEMM
    u16* featTh = (u16*)(ws + 0);          // 4 MB
    u16* featTl = (u16*)(ws + 4194304);    // 4 MB
    u16* mem2   = (u16*)(ws + 8388608);    // 4 MB (bf16)
    float* rawp = (float*)(ws + 12582912); // 13.1 MB
    u16* wch    = (u16*)(ws + 25690112);   // 352 KB
    u16* wcl    = (u16*)(ws + 26050560);   // 352 KB
    float* bcat = (float*)(ws + 26411008); // 2.8 KB
    u16* pwh    = (u16*)(ws + 26413824);   // 128 KB
    u16* pwl    = (u16*)(ws + 26544896);   // 128 KB
    u16* preH   = featTh;                  // alias (featT consumed before sampling)

    // input conversions (feat transpose + all weights), one launch
    prep_k<<<dim3(752), dim3(256), 0, stream>>>(feat, vw, vb, adw, adb, atw, atb,
                                                sw, sb, pw, featTh, featTl,
                                                wch, wcl, bcat, pwh, pwl);
    // all projections; value cols 1-MFMA -> bf16 mem2, rest 3-MFMA -> rawp
    // 32x64 wave tiles: 2816 waves (~11/CU) for global-load latency hiding
    mgemm0_k<<<dim3(256, 11), dim3(64), 0, stream>>>(featTh, featTl, wch, wcl, bcat,
                                                     mem2, rawp);
    // sampling -> preT bf16 (reuses featTh region)
    sample4_k<<<dim3(2048), dim3(256), 0, stream>>>(mem2, rawp, preH);
    // out projection + BN (pw split x pre single = 2 MFMAs)
    mgemm1_k<<<dim3(4, 128), dim3(64), 0, stream>>>(pwh, pwl, preH, gamma, beta, out);
}

// Round 8
// 70.200 us; speedup vs baseline: 1.4085x; 1.0496x over previous
//
#include <hip/hip_runtime.h>
#include <math.h>

#define LL 4096      // H*W
#define KK 256       // C
#define HH 64
#define WW 64
#define NHEAD 8
#define NPNT 16
#define HD 32        // C / NH
#define AST 272      // LDS A-tile row stride in u16 (544 B: 16B-aligned, 4-way bank alias)

typedef unsigned short u16;
typedef __attribute__((ext_vector_type(8))) short sh8;
typedef __attribute__((ext_vector_type(4))) float f32x4;

__device__ __forceinline__ u16 f2bf(float x) {
    union { float f; unsigned u; } v; v.f = x;
    unsigned r = v.u + 0x7FFFu + ((v.u >> 16) & 1u);
    return (u16)(r >> 16);
}
__device__ __forceinline__ float bf2f(u16 h) {
    union { unsigned u; float f; } v; v.u = ((unsigned)h) << 16;
    return v.f;
}

// ---------------------------------------------------------------------------
// wprep_k: weights -> bf16 hi/lo.
// Rows [0,768): wcat = [value 256 | offset 256 | att 128 | size 16 | zero 112]
//   (+ bcat bias, zero-padded). Rows [768,1024): pw -> pwh/pwl.
// ---------------------------------------------------------------------------
__global__ __launch_bounds__(256) void wprep_k(
    const float* __restrict__ vw,  const float* __restrict__ vb,
    const float* __restrict__ adw, const float* __restrict__ adb,
    const float* __restrict__ atw, const float* __restrict__ atb,
    const float* __restrict__ sw,  const float* __restrict__ sb,
    const float* __restrict__ pw,
    u16* __restrict__ wh, u16* __restrict__ wl,
    float* __restrict__ bcat,
    u16* __restrict__ ph, u16* __restrict__ pl)
{
    const int row = blockIdx.x * 4 + (threadIdx.x >> 6);  // 0..1023
    const int c   = threadIdx.x & 63;

    const float* src = nullptr;
    float bv = 0.f;
    u16* dh; u16* dl;
    int drow;

    if (row < 768) {
        const int o = row;
        if (o < 256)      { src = vw  + (size_t)o * KK;        bv = vb[o]; }
        else if (o < 512) { src = adw + (size_t)(o-256) * KK;  bv = adb[o-256]; }
        else if (o < 640) { src = atw + (size_t)(o-512) * KK;  bv = atb[o-512]; }
        else if (o < 656) { src = sw  + (size_t)(o-640) * KK;  bv = sb[o-640]; }
        dh = wh; dl = wl; drow = o;
        if (c == 0) bcat[o] = bv;
    } else {
        const int o = row - 768;
        src = pw + (size_t)o * KK;
        dh = ph; dl = pl; drow = o;
    }

    float4 v = {0.f, 0.f, 0.f, 0.f};
    if (src) v = *(const float4*)(src + c * 4);
    ushort4 hi, lo;
    float x;
    x = v.x; hi.x = f2bf(x); lo.x = f2bf(x - bf2f(hi.x));
    x = v.y; hi.y = f2bf(x); lo.y = f2bf(x - bf2f(hi.y));
    x = v.z; hi.z = f2bf(x); lo.z = f2bf(x - bf2f(hi.z));
    x = v.w; hi.w = f2bf(x); lo.w = f2bf(x - bf2f(hi.w));
    const size_t off = (size_t)drow * KK + c * 4;
    *(ushort4*)(dh + off) = hi;
    *(ushort4*)(dl + off) = lo;
}

// ---------------------------------------------------------------------------
// projf_k: fused feat-transpose + projection GEMM.
// Block = 256 thr (4 waves), BM=32 px, n-group of 256 cols.
// grid.x = 768 flat: gy = bx % 3 (group, INNER for feat L2 reuse), mb = bx/3.
//   gy==0: value cols 0..255, 1 MFMA (hi*hi), bf16 -> mem2
//   gy==1: offset cols 256..511, 3-MFMA split -> rawp ch 16..271
//   gy==2: att/size cols 512..767, 3-MFMA split -> rawp ch 272..399 / 0..15
// Stage: each thread owns one px column, 32 k-values per pass (8 passes via
// tid>>5), converts f32->hi/lo, writes contiguous 64 B per plane (b128s).
// K-loop: A from LDS (ds_read_b128), B (wcat) from L2.
// ---------------------------------------------------------------------------
__global__ __launch_bounds__(256) void projf_k(
    const float* __restrict__ feat,
    const u16* __restrict__ Wh, const u16* __restrict__ Wl,
    const float* __restrict__ bias,
    u16* __restrict__ mem2, float* __restrict__ rawp)
{
    __shared__ u16 Ah[32][AST];
    __shared__ u16 Al[32][AST];

    const int bx = blockIdx.x;
    const int gy = bx % 3;
    const int mb = bx / 3;
    const int m0g = mb * 32;          // global pixel base
    const int b   = m0g >> 12;
    const int l0  = m0g & (LL - 1);
    const int tid = threadIdx.x;
    const bool VAL = (gy == 0);

    // ---- stage A tile: 32 px x 256 k ----
    {
        const int px = tid & 31;
        const int kb = (tid >> 5) * 32;   // 8 groups x 32 k
        const float* fp = feat + ((size_t)(b * KK + kb)) * LL + l0 + px;
        #pragma unroll
        for (int cch = 0; cch < 4; ++cch) {       // 4 chunks of 8 k
            float xs[8];
            #pragma unroll
            for (int j = 0; j < 8; ++j)
                xs[j] = fp[(size_t)(cch * 8 + j) * LL];
            sh8 hv, lv;
            #pragma unroll
            for (int j = 0; j < 8; ++j) {
                u16 h = f2bf(xs[j]);
                hv[j] = (short)h;
                lv[j] = (short)f2bf(xs[j] - bf2f(h));
            }
            *(sh8*)&Ah[px][kb + cch * 8] = hv;
            if (!VAL) *(sh8*)&Al[px][kb + cch * 8] = lv;
        }
    }
    __syncthreads();

    // ---- K-loop ----
    const int lam  = tid & 63;
    const int wave = tid >> 6;
    const int row  = lam & 15;
    const int kq   = (lam >> 4) * 8;
    const int n0   = gy * 256 + wave * 64;

    f32x4 acc[2][4];
    #pragma unroll
    for (int i = 0; i < 2; ++i)
        #pragma unroll
        for (int j = 0; j < 4; ++j)
            acc[i][j] = (f32x4){0.f, 0.f, 0.f, 0.f};

    #pragma unroll
    for (int s = 0; s < 8; ++s) {
        const int k0 = s * 32;
        sh8 ah[2], bh[4];
        #pragma unroll
        for (int mf = 0; mf < 2; ++mf)
            ah[mf] = *(const sh8*)&Ah[mf * 16 + row][k0 + kq];
        #pragma unroll
        for (int nf = 0; nf < 4; ++nf)
            bh[nf] = *(const sh8*)(Wh + ((size_t)(n0 + nf * 16 + row)) * KK + k0 + kq);

        if (VAL) {
            #pragma unroll
            for (int mf = 0; mf < 2; ++mf)
                #pragma unroll
                for (int nf = 0; nf < 4; ++nf)
                    acc[mf][nf] = __builtin_amdgcn_mfma_f32_16x16x32_bf16(ah[mf], bh[nf], acc[mf][nf], 0, 0, 0);
        } else {
            sh8 al[2], bl[4];
            #pragma unroll
            for (int mf = 0; mf < 2; ++mf)
                al[mf] = *(const sh8*)&Al[mf * 16 + row][k0 + kq];
            #pragma unroll
            for (int nf = 0; nf < 4; ++nf)
                bl[nf] = *(const sh8*)(Wl + ((size_t)(n0 + nf * 16 + row)) * KK + k0 + kq);
            #pragma unroll
            for (int mf = 0; mf < 2; ++mf)
                #pragma unroll
                for (int nf = 0; nf < 4; ++nf) {
                    acc[mf][nf] = __builtin_amdgcn_mfma_f32_16x16x32_bf16(ah[mf], bh[nf], acc[mf][nf], 0, 0, 0);
                    acc[mf][nf] = __builtin_amdgcn_mfma_f32_16x16x32_bf16(ah[mf], bl[nf], acc[mf][nf], 0, 0, 0);
                    acc[mf][nf] = __builtin_amdgcn_mfma_f32_16x16x32_bf16(al[mf], bh[nf], acc[mf][nf], 0, 0, 0);
                }
        }
    }

    // ---- epilogue ----
    float bj[4];
    #pragma unroll
    for (int nf = 0; nf < 4; ++nf) bj[nf] = bias[n0 + nf * 16 + row];

    #pragma unroll
    for (int mf = 0; mf < 2; ++mf)
        #pragma unroll
        for (int r = 0; r < 4; ++r) {
            const int m  = m0g + mf * 16 + 4 * (lam >> 4) + r;
            const int bb = m >> 12;
            const int ll = m & (LL - 1);
            #pragma unroll
            for (int nf = 0; nf < 4; ++nf) {
                const int o = n0 + nf * 16 + row;
                const float v = acc[mf][nf][r] + bj[nf];
                if (VAL) {
                    mem2[(((size_t)(bb * NHEAD + (o >> 5)) * LL + ll) * HD) + (o & 31)] = f2bf(v);
                } else if (o < 640) {
                    rawp[((size_t)(bb * LL + ll)) * 400 + (o - 240)] = v;   // offset/att
                } else if (o < 656) {
                    rawp[((size_t)(bb * LL + ll)) * 400 + (o - 640)] = v;   // size
                }   // o >= 656: zero-pad, skip
            }
        }
}

// ---------------------------------------------------------------------------
// Out projection + BN: A = pw hi/lo (M=256 ch), B = preT bf16 single
// (N=8192 pixels), 2 MFMAs per fragment pair. (unchanged from round 5)
// ---------------------------------------------------------------------------
__global__ __launch_bounds__(64) void mgemm1_k(
    const u16* __restrict__ Ah, const u16* __restrict__ Al,
    const u16* __restrict__ Bh,
    const float* __restrict__ gamma, const float* __restrict__ beta,
    float* __restrict__ out)
{
    const int lam = threadIdx.x;
    const int m0 = blockIdx.x * 64;
    const int n0 = blockIdx.y * 64;
    const int row = lam & 15;
    const int kq  = (lam >> 4) * 8;

    f32x4 acc[4][4];
    #pragma unroll
    for (int i = 0; i < 4; ++i)
        #pragma unroll
        for (int j = 0; j < 4; ++j)
            acc[i][j] = (f32x4){0.f, 0.f, 0.f, 0.f};

    #pragma unroll
    for (int s = 0; s < 8; ++s) {
        const int k0 = s * 32;
        sh8 ah[4], al[4], bh[4];
        #pragma unroll
        for (int mf = 0; mf < 4; ++mf) {
            const size_t off = ((size_t)(m0 + mf * 16 + row)) * KK + k0 + kq;
            ah[mf] = *(const sh8*)(Ah + off);
            al[mf] = *(const sh8*)(Al + off);
        }
        #pragma unroll
        for (int nf = 0; nf < 4; ++nf)
            bh[nf] = *(const sh8*)(Bh + ((size_t)(n0 + nf * 16 + row)) * KK + k0 + kq);
        #pragma unroll
        for (int mf = 0; mf < 4; ++mf)
            #pragma unroll
            for (int nf = 0; nf < 4; ++nf) {
                acc[mf][nf] = __builtin_amdgcn_mfma_f32_16x16x32_bf16(ah[mf], bh[nf], acc[mf][nf], 0, 0, 0);
                acc[mf][nf] = __builtin_amdgcn_mfma_f32_16x16x32_bf16(al[mf], bh[nf], acc[mf][nf], 0, 0, 0);
            }
    }

    #pragma unroll
    for (int mf = 0; mf < 4; ++mf)
        #pragma unroll
        for (int r = 0; r < 4; ++r) {
            const int o = m0 + mf * 16 + 4 * (lam >> 4) + r;   // channel
            const float sc = gamma[o] / sqrtf(1.f + 1e-5f);
            const float be = beta[o];
            #pragma unroll
            for (int nf = 0; nf < 4; ++nf) {
                const int lg = n0 + nf * 16 + row;             // global pixel
                const int b  = lg >> 12;
                const int ll = lg & (LL - 1);
                out[((size_t)(b * KK + o)) * LL + ll] = acc[mf][nf][r] * sc + be;
            }
        }
}

// ---------------------------------------------------------------------------
// Sampling: phase 1 (per (group,point) task, shfl softmax) -> LDS records;
// phase 2: 8 lanes/group, ushort4 bf16 gathers from mem2; emits preT bf16.
// rawp pixel-major: c 0..15 size, 16..271 offset, 272..399 att. (unchanged)
// ---------------------------------------------------------------------------
__global__ __launch_bounds__(256) void sample4_k(
    const u16* __restrict__ mem2,
    const float* __restrict__ rawp,
    u16* __restrict__ preH)
{
    __shared__ int   soff[32][17][4];
    __shared__ float swt[32][17][4];

    const int tid = threadIdx.x;

    #pragma unroll
    for (int q = 0; q < 2; ++q) {
        const int t  = q * 256 + tid;
        const int gi = t >> 4;
        const int p  = t & 15;
        const int g  = blockIdx.x * 32 + gi;
        const int l  = g & (LL - 1);
        const int h  = (g >> 12) & (NHEAD - 1);
        const int b  = g >> 15;
        const float* rb = rawp + ((size_t)(b * LL + l)) * 400;

        float logit = rb[272 + h * NPNT + p];
        float m = logit;
        m = fmaxf(m, __shfl_xor(m, 1));
        m = fmaxf(m, __shfl_xor(m, 2));
        m = fmaxf(m, __shfl_xor(m, 4));
        m = fmaxf(m, __shfl_xor(m, 8));
        float e = __expf(logit - m);
        float s = e;
        s += __shfl_xor(s, 1);
        s += __shfl_xor(s, 2);
        s += __shfl_xor(s, 4);
        s += __shfl_xor(s, 8);
        const float wp = e / s;

        float s0 = rb[h * 2 + 0];
        float s1 = rb[h * 2 + 1];
        s0 = fminf(fmaxf(1.f / (1.f + __expf(-s0)), 0.25f), 0.75f);
        s1 = fminf(fmaxf(1.f / (1.f + __expf(-s1)), 0.25f), 0.75f);

        float o0 = rb[16 + (h * NPNT + p) * 2 + 0];
        float o1 = rb[16 + (h * NPNT + p) * 2 + 1];
        o0 = 1.f / (1.f + __expf(-o0));
        o1 = 1.f / (1.f + __expf(-o1));

        const int xl = l & (WW - 1);
        const int yl = l >> 6;
        const float cx = ((float)xl + 0.5f) / ((float)WW + 1e-6f);
        const float cy = ((float)yl + 0.5f) / ((float)HH + 1e-6f);

        float gx = fminf(fmaxf(cx - 0.5f * s0 + o0 * s0, 0.f), 1.f);
        float gy = fminf(fmaxf(cy - 0.5f * s1 + o1 * s1, 0.f), 1.f);
        const float ix = gx * (float)(WW - 1);
        const float iy = gy * (float)(HH - 1);
        const float x0f = floorf(ix);
        const float y0f = floorf(iy);
        const float wx = ix - x0f;
        const float wy = iy - y0f;
        int x0 = min(max((int)x0f, 0), WW - 1);
        int x1 = min(x0 + 1, WW - 1);
        int y0 = min(max((int)y0f, 0), HH - 1);
        int y1 = min(y0 + 1, HH - 1);

        soff[gi][p][0] = (y0 * WW + x0) * HD;
        soff[gi][p][1] = (y0 * WW + x1) * HD;
        soff[gi][p][2] = (y1 * WW + x0) * HD;
        soff[gi][p][3] = (y1 * WW + x1) * HD;
        swt[gi][p][0] = wp * (1.f - wx) * (1.f - wy);
        swt[gi][p][1] = wp * wx * (1.f - wy);
        swt[gi][p][2] = wp * (1.f - wx) * wy;
        swt[gi][p][3] = wp * wx * wy;
    }
    __syncthreads();

    const int gi = tid >> 3;
    const int dq = (tid & 7) * 4;
    const int g  = blockIdx.x * 32 + gi;
    const int l  = g & (LL - 1);
    const int h  = (g >> 12) & (NHEAD - 1);
    const int b  = g >> 15;
    const u16* mb = mem2 + (size_t)(b * NHEAD + h) * LL * HD + dq;

    float4 acc = {0.f, 0.f, 0.f, 0.f};
    #pragma unroll
    for (int p = 0; p < NPNT; ++p) {
        const int4   off = *(const int4*)&soff[gi][p][0];
        const float4 w   = *(const float4*)&swt[gi][p][0];
        const ushort4 q00 = *(const ushort4*)(mb + off.x);
        const ushort4 q01 = *(const ushort4*)(mb + off.y);
        const ushort4 q10 = *(const ushort4*)(mb + off.z);
        const ushort4 q11 = *(const ushort4*)(mb + off.w);
        acc.x += w.x * bf2f(q00.x) + w.y * bf2f(q01.x) + w.z * bf2f(q10.x) + w.w * bf2f(q11.x);
        acc.y += w.x * bf2f(q00.y) + w.y * bf2f(q01.y) + w.z * bf2f(q10.y) + w.w * bf2f(q11.y);
        acc.z += w.x * bf2f(q00.z) + w.y * bf2f(q01.z) + w.z * bf2f(q10.z) + w.w * bf2f(q11.z);
        acc.w += w.x * bf2f(q00.w) + w.y * bf2f(q01.w) + w.z * bf2f(q10.w) + w.w * bf2f(q11.w);
    }

    ushort4 hi;
    hi.x = f2bf(acc.x); hi.y = f2bf(acc.y); hi.z = f2bf(acc.z); hi.w = f2bf(acc.w);
    *(ushort4*)(preH + ((size_t)(b * LL + l)) * KK + h * HD + dq) = hi;
}

extern "C" void kernel_launch(void* const* d_in, const int* in_sizes, int n_in,
                              void* d_out, int out_size, void* d_ws, size_t ws_size,
                              hipStream_t stream) {
    const float* feat  = (const float*)d_in[0];
    const float* vw    = (const float*)d_in[1];
    const float* vb    = (const float*)d_in[2];
    const float* sw    = (const float*)d_in[3];
    const float* sb    = (const float*)d_in[4];
    const float* adw   = (const float*)d_in[5];
    const float* adb   = (const float*)d_in[6];
    const float* atw   = (const float*)d_in[7];
    const float* atb   = (const float*)d_in[8];
    const float* pw    = (const float*)d_in[9];
    const float* gamma = (const float*)d_in[10];
    const float* beta  = (const float*)d_in[11];
    float* out = (float*)d_out;
    char* ws = (char*)d_ws;

    // workspace layout (bytes)
    u16* mem2   = (u16*)(ws + 0);          // 4 MB (bf16)
    float* rawp = (float*)(ws + 4194304);  // 13.1 MB
    u16* preH   = (u16*)(ws + 17301504);   // 4 MB
    u16* wch    = (u16*)(ws + 21495808);   // 384 KB (768 rows)
    u16* wcl    = (u16*)(ws + 21889024);   // 384 KB
    float* bcat = (float*)(ws + 22282240); // 3 KB
    u16* pwh    = (u16*)(ws + 22285312);   // 128 KB
    u16* pwl    = (u16*)(ws + 22416384);   // 128 KB

    // weights -> bf16 hi/lo (tiny)
    wprep_k<<<dim3(256), dim3(256), 0, stream>>>(vw, vb, adw, adb, atw, atb,
                                                 sw, sb, pw, wch, wcl, bcat, pwh, pwl);
    // fused feat-stage + all projections
    projf_k<<<dim3(768), dim3(256), 0, stream>>>(feat, wch, wcl, bcat, mem2, rawp);
    // sampling -> preT bf16
    sample4_k<<<dim3(2048), dim3(256), 0, stream>>>(mem2, rawp, preH);
    // out projection + BN
    mgemm1_k<<<dim3(4, 128), dim3(64), 0, stream>>>(pwh, pwl, preH, gamma, beta, out);
}